// Round 3
// baseline (259.898 us; speedup 1.0000x reference)
//
#include <hip/hip_runtime.h>
#include <hip/hip_cooperative_groups.h>

namespace cg = cooperative_groups;

static constexpr int   H         = 4096;
static constexpr int   MAX_STEPS = 16;
static constexpr float EPS       = 0.01f;

static constexpr int TPB   = 256;    // A/B: 4 waves/block, 1 wave per row
static constexpr int NB    = H / 4;  // 1024 blocks
static constexpr int TPB_C = 1024;   // C: 16 waves/block (R2-proven coop shape)
static constexpr int NB_C  = 256;    // 1 block/CU

// ws layout (floats):
//   v0[H] | hbuf[2][H] | part0[NB] | part1[NB] | partC[MAX_STEPS][NB_C] | CTRL[2]
static constexpr int WS_V0   = 0;
static constexpr int WS_HB   = H;                       // hbuf[b] at WS_HB + b*H
static constexpr int WS_P0   = 3 * H;
static constexpr int WS_P1   = 3 * H + NB;
static constexpr int WS_PC   = 3 * H + 2 * NB;
static constexpr int WS_CTRL = WS_PC + MAX_STEPS * NB_C; // [0]=halted N (-1 if none), [1]=cum0

__device__ __forceinline__ float wave_reduce(float v) {
    #pragma unroll
    for (int off = 32; off > 0; off >>= 1) v += __shfl_down(v, off);
    return v;
}
__device__ __forceinline__ float sigmoidf(float z) { return 1.f / (1.f + __expf(-z)); }

// ==================== A: init + step 0 fused ====================
// v0 = W_ih[:,1:]@x + b_ih + b_hh ; h1 = tanh(v0 + W_ih[:,0] + W_hh@s) ; part0
__global__ void __launch_bounds__(TPB, 4)
k_init0(const float* __restrict__ x,   const float* __restrict__ s,
        const float* __restrict__ Wih, const float* __restrict__ bih,
        const float* __restrict__ Whh, const float* __restrict__ bhh,
        const float* __restrict__ whalt, float* __restrict__ ws)
{
    __shared__ float xs[H];
    __shared__ float ss[H];
    __shared__ float hred[4];
    const int tid = threadIdx.x, lane = tid & 63, wave = tid >> 6;
    const int row = blockIdx.x * 4 + wave;

    for (int i = tid; i < H / 4; i += TPB) {
        ((float4*)xs)[i] = ((const float4*)x)[i];
        ((float4*)ss)[i] = ((const float4*)s)[i];
    }
    __syncthreads();

    // --- dot 1: W_ih[row][1:] @ x  (row stride H+1 = 4097, unaligned) ---
    const long long off0 = (long long)row * (H + 1) + 1;
    const int a = (int)((4 - (off0 & 3)) & 3);
    float acc_ih = 0.f;
    if (lane < a) acc_ih += Wih[off0 + lane] * xs[lane];
    const int nvec = (H - a) >> 2;
    const float4* wv = (const float4*)(Wih + off0 + a);
    for (int i = lane; i < nvec; i += 64) {
        float4 w  = wv[i];
        const int e = a + i * 4;
        acc_ih = fmaf(w.x, xs[e],     acc_ih);
        acc_ih = fmaf(w.y, xs[e + 1], acc_ih);
        acc_ih = fmaf(w.z, xs[e + 2], acc_ih);
        acc_ih = fmaf(w.w, xs[e + 3], acc_ih);
    }
    const int tail  = (H - a) & 3;
    const int tbase = a + nvec * 4;
    if (lane < tail) acc_ih += Wih[off0 + tbase + lane] * xs[tbase + lane];
    acc_ih = wave_reduce(acc_ih);

    // --- dot 2: W_hh[row] @ s  (aligned, 16 loads in flight) ---
    const float4* Wr = (const float4*)(Whh + (size_t)row * H);
    float4 w[16];
    #pragma unroll
    for (int it = 0; it < 16; ++it) w[it] = Wr[it * 64 + lane];
    float acc_hh = 0.f;
    #pragma unroll
    for (int it = 0; it < 16; ++it) {
        float4 hv = ((const float4*)ss)[it * 64 + lane];
        acc_hh = fmaf(w[it].x, hv.x, acc_hh);
        acc_hh = fmaf(w[it].y, hv.y, acc_hh);
        acc_hh = fmaf(w[it].z, hv.z, acc_hh);
        acc_hh = fmaf(w[it].w, hv.w, acc_hh);
    }
    acc_hh = wave_reduce(acc_hh);

    if (lane == 0) {
        const float v0 = acc_ih + bih[row] + bhh[row];
        ws[WS_V0 + row] = v0;
        const float wih0 = Wih[(long long)row * (H + 1)];   // W_ih[row][0]
        const float h1 = tanhf(v0 + wih0 + acc_hh);
        ws[WS_HB + 1 * H + row] = h1;                        // hbuf[1] = h after step 0
        hred[wave] = whalt[row] * h1;
    }
    __syncthreads();
    if (tid == 0)
        ws[WS_P0 + blockIdx.x] = hred[0] + hred[1] + hred[2] + hred[3];
}

// ==================== B: decide step 0, compute step 1 ====================
__global__ void __launch_bounds__(TPB, 4)
k_step1(const float* __restrict__ Whh, const float* __restrict__ whalt,
        const float* __restrict__ bhalt, float* __restrict__ ws)
{
    __shared__ float hs[H];
    __shared__ float hred[4];
    const int tid = threadIdx.x, lane = tid & 63, wave = tid >> 6;
    const float bh = bhalt[0];

    // reduce part0[1024] (identical order in every block -> uniform decision)
    float p = 0.f;
    #pragma unroll
    for (int k = 0; k < NB / TPB; ++k) p += ws[WS_P0 + tid + k * TPB];
    p = wave_reduce(p);
    if (lane == 0) hred[wave] = p;
    __syncthreads();
    const float total0 = hred[0] + hred[1] + hred[2] + hred[3];
    const float cum0 = sigmoidf(total0 + bh);
    const bool halted0 = (cum0 >= 1.f - EPS);
    if (blockIdx.x == 0 && tid == 0) {
        ws[WS_CTRL]     = halted0 ? 0.f : -1.f;
        ws[WS_CTRL + 1] = cum0;
    }
    if (halted0) return;
    __syncthreads();                 // hred reused below

    // heavy: h2 = tanh(v0 + W_hh @ h1)
    const float* hin = ws + WS_HB + 1 * H;         // hbuf[1]
    for (int i = tid; i < H / 4; i += TPB)
        ((float4*)hs)[i] = ((const float4*)hin)[i];
    __syncthreads();

    const int row = blockIdx.x * 4 + wave;
    const float4* Wr = (const float4*)(Whh + (size_t)row * H);
    float4 w[16];
    #pragma unroll
    for (int it = 0; it < 16; ++it) w[it] = Wr[it * 64 + lane];
    float acc = 0.f;
    #pragma unroll
    for (int it = 0; it < 16; ++it) {
        float4 hv = ((const float4*)hs)[it * 64 + lane];
        acc = fmaf(w[it].x, hv.x, acc);
        acc = fmaf(w[it].y, hv.y, acc);
        acc = fmaf(w[it].z, hv.z, acc);
        acc = fmaf(w[it].w, hv.w, acc);
    }
    acc = wave_reduce(acc);
    if (lane == 0) {
        const float h2 = tanhf(acc + ws[WS_V0 + row]);
        ws[WS_HB + 0 * H + row] = h2;              // hbuf[0] = h after step 1
        hred[wave] = whalt[row] * h2;
    }
    __syncthreads();
    if (tid == 0)
        ws[WS_P1 + blockIdx.x] = hred[0] + hred[1] + hred[2] + hred[3];
}

// ==================== C: cooperative tail — decide N, rare late steps, final ====================
// Common case (N<=1): NO grid.sync is ever executed; C = one decision round + final matvec.
__global__ void __launch_bounds__(TPB_C, 4)
k_tail(const float* __restrict__ Whh,   const float* __restrict__ whalt,
       const float* __restrict__ bhalt, const float* __restrict__ Wout,
       const float* __restrict__ bout,  float* __restrict__ ws,
       float* __restrict__ out)
{
    cg::grid_group grid = cg::this_grid();
    __shared__ float sh[H];
    __shared__ float hred[16];
    const int tid = threadIdx.x, lane = tid & 63, wave = tid >> 6;
    const int row = blockIdx.x * 16 + wave;
    const float bh = bhalt[0];

    const float ctrl0 = ws[WS_CTRL];
    int N;
    if (ctrl0 >= 0.f) {
        N = (int)ctrl0;                            // halted at step 0
    } else {
        // decide step 1: reduce part1[1024], one element per thread
        float p = ws[WS_P1 + tid];
        p = wave_reduce(p);
        if (lane == 0) hred[wave] = p;
        __syncthreads();
        float total1 = 0.f;
        #pragma unroll
        for (int j = 0; j < 16; ++j) total1 += hred[j];
        float cum = ws[WS_CTRL + 1] + sigmoidf(total1 + bh);
        __syncthreads();                           // hred reads done before any reuse
        if (cum >= 1.f - EPS) {
            N = 1;
        } else {
            // rare path: steps 2..15 with grid-wide sync
            N = MAX_STEPS - 1;
            for (int t = 2; t < MAX_STEPS; ++t) {
                const float* hin = ws + WS_HB + (size_t)(t & 1) * H;
                for (int i = tid; i < H / 4; i += TPB_C)
                    ((float4*)sh)[i] = ((const float4*)hin)[i];
                __syncthreads();

                const float4* Wr = (const float4*)(Whh + (size_t)row * H);
                float4 w[16];
                #pragma unroll
                for (int it = 0; it < 16; ++it) w[it] = Wr[it * 64 + lane];
                float a2 = 0.f;
                #pragma unroll
                for (int it = 0; it < 16; ++it) {
                    float4 hv = ((const float4*)sh)[it * 64 + lane];
                    a2 = fmaf(w[it].x, hv.x, a2);
                    a2 = fmaf(w[it].y, hv.y, a2);
                    a2 = fmaf(w[it].z, hv.z, a2);
                    a2 = fmaf(w[it].w, hv.w, a2);
                }
                a2 = wave_reduce(a2);
                if (lane == 0) {
                    const float hval = tanhf(a2 + ws[WS_V0 + row]);
                    ws[WS_HB + (size_t)((t + 1) & 1) * H + row] = hval;
                    hred[wave] = whalt[row] * hval;
                }
                __syncthreads();
                if (tid == 0) {
                    float v = 0.f;
                    #pragma unroll
                    for (int j = 0; j < 16; ++j) v += hred[j];
                    ws[WS_PC + t * NB_C + blockIdx.x] = v;
                }
                grid.sync();                       // h_{t+1} + partials visible

                float q = (tid < NB_C) ? ws[WS_PC + t * NB_C + tid] : 0.f;
                q = wave_reduce(q);
                if (lane == 0) hred[wave] = q;
                __syncthreads();
                float tot = 0.f;
                #pragma unroll
                for (int j = 0; j < 16; ++j) tot += hred[j];
                cum += sigmoidf(tot + bh);
                __syncthreads();                   // hred + sh reads done before next iter
                if (cum >= 1.f - EPS) { N = t; break; }
            }
        }
    }

    // final: out = W_out @ h_N + b_out ; s_new = h_N ; ponder = N
    const float* hN = ws + WS_HB + (size_t)((N + 1) & 1) * H;
    for (int i = tid; i < H / 4; i += TPB_C)
        ((float4*)sh)[i] = ((const float4*)hN)[i];
    __syncthreads();

    const float4* Wr = (const float4*)(Wout + (size_t)row * H);
    float4 w[16];
    #pragma unroll
    for (int it = 0; it < 16; ++it) w[it] = Wr[it * 64 + lane];
    float a3 = 0.f;
    #pragma unroll
    for (int it = 0; it < 16; ++it) {
        float4 hv = ((const float4*)sh)[it * 64 + lane];
        a3 = fmaf(w[it].x, hv.x, a3);
        a3 = fmaf(w[it].y, hv.y, a3);
        a3 = fmaf(w[it].z, hv.z, a3);
        a3 = fmaf(w[it].w, hv.w, a3);
    }
    a3 = wave_reduce(a3);
    if (lane == 0) {
        out[row]     = a3 + bout[row];
        out[H + row] = sh[row];
        if (row == 0) out[2 * H] = (float)N;
    }
}

// ==================== fallback: proven multi-dispatch path ====================
static constexpr int SLOTS       = 64;
static constexpr int SLOT_STRIDE = 32;
static constexpr int FWS_V0   = 0;
static constexpr int FWS_WIH0 = H;
static constexpr int FWS_TOT  = 2 * H;
static constexpr int FWS_PART = 2 * H + 32;
static constexpr int FWS_H    = FWS_PART + MAX_STEPS * SLOTS * SLOT_STRIDE;

__global__ void __launch_bounds__(TPB)
k_init(const float* __restrict__ x, const float* __restrict__ s,
       const float* __restrict__ Wih, const float* __restrict__ bih,
       const float* __restrict__ bhh, float* __restrict__ ws)
{
    __shared__ float xs[H];
    const int tid = threadIdx.x, lane = tid & 63, wave = tid >> 6;
    const int row = blockIdx.x * 4 + wave;

    for (int i = tid; i < H / 4; i += TPB)
        ((float4*)xs)[i] = ((const float4*)x)[i];
    __syncthreads();

    const long long off0 = (long long)row * (H + 1) + 1;
    const int a = (int)((4 - (off0 & 3)) & 3);
    float acc = 0.f;
    if (lane < a) acc += Wih[off0 + lane] * xs[lane];
    const int nvec = (H - a) >> 2;
    const float4* wv = (const float4*)(Wih + off0 + a);
    for (int i = lane; i < nvec; i += 64) {
        float4 w  = wv[i];
        const int e = a + i * 4;
        acc = fmaf(w.x, xs[e],     acc);
        acc = fmaf(w.y, xs[e + 1], acc);
        acc = fmaf(w.z, xs[e + 2], acc);
        acc = fmaf(w.w, xs[e + 3], acc);
    }
    const int tail  = (H - a) & 3;
    const int tbase = a + nvec * 4;
    if (lane < tail) acc += Wih[off0 + tbase + lane] * xs[tbase + lane];
    acc = wave_reduce(acc);
    if (lane == 0) {
        ws[FWS_V0 + row]   = acc + bih[row] + bhh[row];
        ws[FWS_WIH0 + row] = Wih[(long long)row * (H + 1)];
    }
    const int gid = blockIdx.x * TPB + tid;
    if (gid < H) ws[FWS_H + gid] = s[gid];
    if (gid < 32 + MAX_STEPS * SLOTS * SLOT_STRIDE) ws[FWS_TOT + gid] = 0.f;
}

__global__ void __launch_bounds__(TPB, 4)
k_step(int t, const float* __restrict__ Whh, const float* __restrict__ whalt,
       const float* __restrict__ bhalt, float* __restrict__ ws)
{
    const float bh = bhalt[0];
    float cum = 0.f;
    for (int j = 0; j < t - 1; ++j) {
        cum += sigmoidf(ws[FWS_TOT + j] + bh);
        if (cum >= 1.f - EPS) return;
    }
    if (t >= 1) {
        float sj = 0.f;
        const float* p = ws + FWS_PART + (size_t)(t - 1) * (SLOTS * SLOT_STRIDE);
        #pragma unroll
        for (int g = 0; g < SLOTS; ++g) sj += p[g * SLOT_STRIDE];
        if (threadIdx.x == 0) ws[FWS_TOT + (t - 1)] = sj;
        cum += sigmoidf(sj + bh);
        if (cum >= 1.f - EPS) return;
    }

    __shared__ float hs[H];
    __shared__ float hred[4];
    const int tid = threadIdx.x, lane = tid & 63, wave = tid >> 6;
    const float* hin  = ws + FWS_H + (size_t)(t & 1) * H;
    float*       hout = ws + FWS_H + (size_t)((t + 1) & 1) * H;
    for (int i = tid; i < H / 4; i += TPB)
        ((float4*)hs)[i] = ((const float4*)hin)[i];
    __syncthreads();

    const int row = blockIdx.x * 4 + wave;
    const float4* Wr = (const float4*)(Whh + (size_t)row * H);
    float4 w[16];
    #pragma unroll
    for (int it = 0; it < 16; ++it) w[it] = Wr[it * 64 + lane];
    float acc = 0.f;
    #pragma unroll
    for (int it = 0; it < 16; ++it) {
        float4 hv = ((const float4*)hs)[it * 64 + lane];
        acc = fmaf(w[it].x, hv.x, acc);
        acc = fmaf(w[it].y, hv.y, acc);
        acc = fmaf(w[it].z, hv.z, acc);
        acc = fmaf(w[it].w, hv.w, acc);
    }
    acc = wave_reduce(acc);
    if (lane == 0) {
        float pre  = acc + ws[FWS_V0 + row] + (t == 0 ? ws[FWS_WIH0 + row] : 0.f);
        float hval = tanhf(pre);
        hout[row]  = hval;
        hred[wave] = whalt[row] * hval;
    }
    __syncthreads();
    if (tid == 0) {
        float v = hred[0] + hred[1] + hred[2] + hred[3];
        atomicAdd(&ws[FWS_PART + (size_t)t * (SLOTS * SLOT_STRIDE)
                      + (blockIdx.x & (SLOTS - 1)) * SLOT_STRIDE], v);
    }
}

__global__ void __launch_bounds__(TPB, 4)
k_final(const float* __restrict__ Wout, const float* __restrict__ bout,
        const float* __restrict__ bhalt, float* __restrict__ ws,
        float* __restrict__ out)
{
    const float bh = bhalt[0];
    float cum = 0.f;
    int N = MAX_STEPS - 1;
    for (int j = 0; j < MAX_STEPS; ++j) {
        float sj;
        if (j < MAX_STEPS - 1) sj = ws[FWS_TOT + j];
        else {
            sj = 0.f;
            const float* p = ws + FWS_PART + (size_t)(MAX_STEPS - 1) * (SLOTS * SLOT_STRIDE);
            #pragma unroll
            for (int g = 0; g < SLOTS; ++g) sj += p[g * SLOT_STRIDE];
        }
        cum += sigmoidf(sj + bh);
        if (cum >= 1.f - EPS) { N = j; break; }
    }

    __shared__ float hs[H];
    const float* hN = ws + FWS_H + (size_t)((N + 1) & 1) * H;
    const int tid = threadIdx.x, lane = tid & 63, wave = tid >> 6;
    for (int i = tid; i < H / 4; i += TPB)
        ((float4*)hs)[i] = ((const float4*)hN)[i];
    __syncthreads();

    const int row = blockIdx.x * 4 + wave;
    const float4* Wr = (const float4*)(Wout + (size_t)row * H);
    float4 w[16];
    #pragma unroll
    for (int it = 0; it < 16; ++it) w[it] = Wr[it * 64 + lane];
    float acc = 0.f;
    #pragma unroll
    for (int it = 0; it < 16; ++it) {
        float4 hv = ((const float4*)hs)[it * 64 + lane];
        acc = fmaf(w[it].x, hv.x, acc);
        acc = fmaf(w[it].y, hv.y, acc);
        acc = fmaf(w[it].z, hv.z, acc);
        acc = fmaf(w[it].w, hv.w, acc);
    }
    acc = wave_reduce(acc);
    if (lane == 0) {
        out[row]     = acc + bout[row];
        out[H + row] = hs[row];
        if (row == 0) out[2 * H] = (float)N;
    }
}

extern "C" void kernel_launch(void* const* d_in, const int* in_sizes, int n_in,
                              void* d_out, int out_size, void* d_ws, size_t ws_size,
                              hipStream_t stream) {
    const float* x     = (const float*)d_in[0];
    const float* s     = (const float*)d_in[1];
    const float* Wih   = (const float*)d_in[2];
    const float* bih   = (const float*)d_in[3];
    const float* Whh   = (const float*)d_in[4];
    const float* bhh   = (const float*)d_in[5];
    const float* whalt = (const float*)d_in[6];
    const float* bhalt = (const float*)d_in[7];
    const float* Wout  = (const float*)d_in[8];
    const float* bout  = (const float*)d_in[9];
    float* out = (float*)d_out;
    float* ws  = (float*)d_ws;

    // Host-side-only capability probe (no stream ops -> graph-capture safe), cached.
    static int use_coop = -1;
    if (use_coop < 0) {
        int dev = 0;  (void)hipGetDevice(&dev);
        int coop = 0; (void)hipDeviceGetAttribute(&coop, hipDeviceAttributeCooperativeLaunch, dev);
        int ncu = 0;  (void)hipDeviceGetAttribute(&ncu, hipDeviceAttributeMultiprocessorCount, dev);
        int maxb = 0;
        (void)hipOccupancyMaxActiveBlocksPerMultiprocessor(&maxb, k_tail, TPB_C, 0);
        use_coop = (coop != 0 && (long long)maxb * (long long)ncu >= NB_C) ? 1 : 0;
    }

    if (use_coop == 1) {
        k_init0<<<NB, TPB, 0, stream>>>(x, s, Wih, bih, Whh, bhh, whalt, ws);
        k_step1<<<NB, TPB, 0, stream>>>(Whh, whalt, bhalt, ws);
        void* args[] = { &Whh, &whalt, &bhalt, &Wout, &bout, &ws, &out };
        hipError_t e = hipLaunchCooperativeKernel((const void*)k_tail, dim3(NB_C),
                                                  dim3(TPB_C), args, 0, stream);
        if (e == hipSuccess) return;
        use_coop = 0;   // rejected synchronously -> full fallback recomputes from scratch
    }

    k_init<<<NB, TPB, 0, stream>>>(x, s, Wih, bih, bhh, ws);
    for (int t = 0; t < MAX_STEPS; ++t)
        k_step<<<NB, TPB, 0, stream>>>(t, Whh, whalt, bhalt, ws);
    k_final<<<NB, TPB, 0, stream>>>(Wout, bout, bhalt, ws, out);
}

// Round 4
// 231.684 us; speedup vs baseline: 1.1218x; 1.1218x over previous
//
#include <hip/hip_runtime.h>

static constexpr int   H         = 4096;
static constexpr int   MAX_STEPS = 16;
static constexpr float EPS       = 0.01f;

static constexpr int TPB   = 256;    // A/B: 4 waves/block, 1 wave per row
static constexpr int NB    = H / 4;  // 1024 blocks
static constexpr int TPB_C = 1024;   // C: 16 waves/block, 1 wave per row
static constexpr int NB_C  = 256;    // 256 blocks -> 1 block/CU (co-resident for rare-path barrier)

// ws layout (floats):
//   v0[H] | hbuf[2][H] | part0[NB] | part1[NB] | partC[MAX_STEPS][NB_C] | CTRL[2] | CNT[16](int)
static constexpr int WS_V0   = 0;
static constexpr int WS_HB   = H;                        // hbuf[b] at WS_HB + b*H
static constexpr int WS_P0   = 3 * H;
static constexpr int WS_P1   = 3 * H + NB;
static constexpr int WS_PC   = 3 * H + 2 * NB;
static constexpr int WS_CTRL = WS_PC + MAX_STEPS * NB_C; // [0]=halted-at-0 flag/N, [1]=cum0
static constexpr int WS_CNT  = WS_CTRL + 2;              // 16 int barrier counters (rare path)

__device__ __forceinline__ float wave_reduce(float v) {
    #pragma unroll
    for (int off = 32; off > 0; off >>= 1) v += __shfl_down(v, off);
    return v;
}
__device__ __forceinline__ float sigmoidf(float z) { return 1.f / (1.f + __expf(-z)); }

// ==================== A: init + step 0 fused ====================
// v0 = W_ih[:,1:]@x + b_ih + b_hh ; h1 = tanh(v0 + W_ih[:,0] + W_hh@s) ; part0
__global__ void __launch_bounds__(TPB, 4)
k_init0(const float* __restrict__ x,   const float* __restrict__ s,
        const float* __restrict__ Wih, const float* __restrict__ bih,
        const float* __restrict__ Whh, const float* __restrict__ bhh,
        const float* __restrict__ whalt, float* __restrict__ ws)
{
    __shared__ float xs[H];
    __shared__ float ss[H];
    __shared__ float hred[4];
    const int tid = threadIdx.x, lane = tid & 63, wave = tid >> 6;
    const int row = blockIdx.x * 4 + wave;

    for (int i = tid; i < H / 4; i += TPB) {
        ((float4*)xs)[i] = ((const float4*)x)[i];
        ((float4*)ss)[i] = ((const float4*)s)[i];
    }
    __syncthreads();

    // --- dot 1: W_ih[row][1:] @ x. Row stride H+1=4097 -> per-row misalignment m.
    // Load via aligned-down base with 16 float4s in flight; shift the x index by m.
    const size_t row_off = (size_t)row * (H + 1);       // W_ih[row][0]
    const size_t start   = row_off + 1;                 // W_ih[row][1]
    const int    m       = (int)(start & 3);            // 0..3
    const float4* wv = (const float4*)(Wih + (start - m));  // 16B-aligned
    float4 w[16];
    #pragma unroll
    for (int it = 0; it < 16; ++it) w[it] = wv[it * 64 + lane];   // 16 loads in flight
    float acc_ih = 0.f;
    {   // it = 0: x-index kb = lane*4 + c - m; only lane 0 has kb<0 for c<m
        const int kb = lane * 4 - m;
        if (kb + 0 >= 0) acc_ih = fmaf(w[0].x, xs[kb + 0], acc_ih);
        if (kb + 1 >= 0) acc_ih = fmaf(w[0].y, xs[kb + 1], acc_ih);
        if (kb + 2 >= 0) acc_ih = fmaf(w[0].z, xs[kb + 2], acc_ih);
        if (kb + 3 >= 0) acc_ih = fmaf(w[0].w, xs[kb + 3], acc_ih);
    }
    #pragma unroll
    for (int it = 1; it < 16; ++it) {                    // fully in-range
        const int kb = it * 256 + lane * 4 - m;
        acc_ih = fmaf(w[it].x, xs[kb + 0], acc_ih);
        acc_ih = fmaf(w[it].y, xs[kb + 1], acc_ih);
        acc_ih = fmaf(w[it].z, xs[kb + 2], acc_ih);
        acc_ih = fmaf(w[it].w, xs[kb + 3], acc_ih);
    }
    if (lane < m)                                        // tail: x-index 4096-m .. 4095
        acc_ih += Wih[start + 4096 - m + lane] * xs[4096 - m + lane];
    acc_ih = wave_reduce(acc_ih);

    // --- dot 2: W_hh[row] @ s (aligned, 16 loads in flight) ---
    const float4* Wr = (const float4*)(Whh + (size_t)row * H);
    float4 w2[16];
    #pragma unroll
    for (int it = 0; it < 16; ++it) w2[it] = Wr[it * 64 + lane];
    float acc_hh = 0.f;
    #pragma unroll
    for (int it = 0; it < 16; ++it) {
        float4 hv = ((const float4*)ss)[it * 64 + lane];
        acc_hh = fmaf(w2[it].x, hv.x, acc_hh);
        acc_hh = fmaf(w2[it].y, hv.y, acc_hh);
        acc_hh = fmaf(w2[it].z, hv.z, acc_hh);
        acc_hh = fmaf(w2[it].w, hv.w, acc_hh);
    }
    acc_hh = wave_reduce(acc_hh);

    if (lane == 0) {
        const float v0 = acc_ih + bih[row] + bhh[row];
        ws[WS_V0 + row] = v0;
        const float wih0 = Wih[row_off];                 // W_ih[row][0]
        const float h1 = tanhf(v0 + wih0 + acc_hh);
        ws[WS_HB + 1 * H + row] = h1;                    // hbuf[1] = h after step 0
        hred[wave] = whalt[row] * h1;
    }
    __syncthreads();
    if (tid == 0)
        ws[WS_P0 + blockIdx.x] = hred[0] + hred[1] + hred[2] + hred[3];
}

// ==================== B: decide step 0, compute step 1 ====================
__global__ void __launch_bounds__(TPB, 4)
k_step1(const float* __restrict__ Whh, const float* __restrict__ whalt,
        const float* __restrict__ bhalt, float* __restrict__ ws)
{
    __shared__ float hs[H];
    __shared__ float hred[4];
    const int tid = threadIdx.x, lane = tid & 63, wave = tid >> 6;
    const float bh = bhalt[0];

    // reduce part0[1024] in identical order in every block -> uniform decision
    float p = 0.f;
    #pragma unroll
    for (int k = 0; k < NB / TPB; ++k) p += ws[WS_P0 + tid + k * TPB];
    p = wave_reduce(p);
    if (lane == 0) hred[wave] = p;
    __syncthreads();
    const float total0 = hred[0] + hred[1] + hred[2] + hred[3];
    const float cum0 = sigmoidf(total0 + bh);
    const bool halted0 = (cum0 >= 1.f - EPS);
    if (blockIdx.x == 0 && tid == 0) {
        ws[WS_CTRL]     = halted0 ? 0.f : -1.f;
        ws[WS_CTRL + 1] = cum0;
    }
    if (halted0) return;
    // zero rare-path barrier counters (ws is poisoned between runs)
    if (blockIdx.x == 0 && tid < MAX_STEPS) ((int*)(ws + WS_CNT))[tid] = 0;
    __syncthreads();                 // hred reused below

    // heavy: h2 = tanh(v0 + W_hh @ h1)
    const float* hin = ws + WS_HB + 1 * H;               // hbuf[1]
    for (int i = tid; i < H / 4; i += TPB)
        ((float4*)hs)[i] = ((const float4*)hin)[i];
    __syncthreads();

    const int row = blockIdx.x * 4 + wave;
    const float4* Wr = (const float4*)(Whh + (size_t)row * H);
    float4 w[16];
    #pragma unroll
    for (int it = 0; it < 16; ++it) w[it] = Wr[it * 64 + lane];
    float acc = 0.f;
    #pragma unroll
    for (int it = 0; it < 16; ++it) {
        float4 hv = ((const float4*)hs)[it * 64 + lane];
        acc = fmaf(w[it].x, hv.x, acc);
        acc = fmaf(w[it].y, hv.y, acc);
        acc = fmaf(w[it].z, hv.z, acc);
        acc = fmaf(w[it].w, hv.w, acc);
    }
    acc = wave_reduce(acc);
    if (lane == 0) {
        const float h2 = tanhf(acc + ws[WS_V0 + row]);
        ws[WS_HB + 0 * H + row] = h2;                    // hbuf[0] = h after step 1
        hred[wave] = whalt[row] * h2;
    }
    __syncthreads();
    if (tid == 0)
        ws[WS_P1 + blockIdx.x] = hred[0] + hred[1] + hred[2] + hred[3];
}

// ---- device-wide barrier for the RARE path only (256 blocks, 1 block/CU, co-resident).
// Distinct counter per step -> no generation/reset hazards. atomicAdd(.,0) = coherent read.
__device__ __forceinline__ void gbarrier(int* cnt) {
    __syncthreads();
    if (threadIdx.x == 0) {
        __threadfence();                         // publish this XCD's dirty lines
        atomicAdd(cnt, 1);
        while (atomicAdd(cnt, 0) < NB_C) __builtin_amdgcn_s_sleep(8);
        __threadfence();                         // acquire
    }
    __syncthreads();
}

// ==================== C: decide step 1; rare steps 2..15; final ====================
// Common case (N<=1): straight-line, zero atomics, zero barriers beyond __syncthreads.
__global__ void __launch_bounds__(TPB_C, 4)
k_tail(const float* __restrict__ Whh,   const float* __restrict__ whalt,
       const float* __restrict__ bhalt, const float* __restrict__ Wout,
       const float* __restrict__ bout,  float* __restrict__ ws,
       float* __restrict__ out)
{
    __shared__ float sh[H];
    __shared__ float hred[16];
    const int tid = threadIdx.x, lane = tid & 63, wave = tid >> 6;
    const int row = blockIdx.x * 16 + wave;
    const float bh = bhalt[0];

    const float ctrl0 = ws[WS_CTRL];
    int N;
    if (ctrl0 >= 0.f) {
        N = (int)ctrl0;                                  // halted at step 0
    } else {
        // decide step 1: reduce part1[1024], one element per thread
        float p = ws[WS_P1 + tid];
        p = wave_reduce(p);
        if (lane == 0) hred[wave] = p;
        __syncthreads();
        float total1 = 0.f;
        #pragma unroll
        for (int j = 0; j < 16; ++j) total1 += hred[j];
        float cum = ws[WS_CTRL + 1] + sigmoidf(total1 + bh);
        __syncthreads();
        if (cum >= 1.f - EPS) {
            N = 1;
        } else {
            // rare path: steps 2..15 with hand-rolled device barrier
            N = MAX_STEPS - 1;
            for (int t = 2; t < MAX_STEPS; ++t) {
                const float* hin = ws + WS_HB + (size_t)(t & 1) * H;
                for (int i = tid; i < H / 4; i += TPB_C)
                    ((float4*)sh)[i] = ((const float4*)hin)[i];
                __syncthreads();

                const float4* Wr = (const float4*)(Whh + (size_t)row * H);
                float4 w[16];
                #pragma unroll
                for (int it = 0; it < 16; ++it) w[it] = Wr[it * 64 + lane];
                float a2 = 0.f;
                #pragma unroll
                for (int it = 0; it < 16; ++it) {
                    float4 hv = ((const float4*)sh)[it * 64 + lane];
                    a2 = fmaf(w[it].x, hv.x, a2);
                    a2 = fmaf(w[it].y, hv.y, a2);
                    a2 = fmaf(w[it].z, hv.z, a2);
                    a2 = fmaf(w[it].w, hv.w, a2);
                }
                a2 = wave_reduce(a2);
                if (lane == 0) {
                    const float hval = tanhf(a2 + ws[WS_V0 + row]);
                    ws[WS_HB + (size_t)((t + 1) & 1) * H + row] = hval;
                    hred[wave] = whalt[row] * hval;
                }
                __syncthreads();
                if (tid == 0) {
                    float v = 0.f;
                    #pragma unroll
                    for (int j = 0; j < 16; ++j) v += hred[j];
                    ws[WS_PC + t * NB_C + blockIdx.x] = v;
                }
                gbarrier((int*)(ws + WS_CNT) + t);       // h_{t+1} + partials visible

                float q = (tid < NB_C) ? ws[WS_PC + t * NB_C + tid] : 0.f;
                q = wave_reduce(q);
                if (lane == 0) hred[wave] = q;
                __syncthreads();
                float tot = 0.f;
                #pragma unroll
                for (int j = 0; j < 16; ++j) tot += hred[j];
                cum += sigmoidf(tot + bh);
                __syncthreads();
                if (cum >= 1.f - EPS) { N = t; break; }
            }
        }
    }

    // final: out = W_out @ h_N + b_out ; s_new = h_N ; ponder = N
    const float* hN = ws + WS_HB + (size_t)((N + 1) & 1) * H;
    for (int i = tid; i < H / 4; i += TPB_C)
        ((float4*)sh)[i] = ((const float4*)hN)[i];
    __syncthreads();

    const float4* Wr = (const float4*)(Wout + (size_t)row * H);
    float4 w[16];
    #pragma unroll
    for (int it = 0; it < 16; ++it) w[it] = Wr[it * 64 + lane];
    float a3 = 0.f;
    #pragma unroll
    for (int it = 0; it < 16; ++it) {
        float4 hv = ((const float4*)sh)[it * 64 + lane];
        a3 = fmaf(w[it].x, hv.x, a3);
        a3 = fmaf(w[it].y, hv.y, a3);
        a3 = fmaf(w[it].z, hv.z, a3);
        a3 = fmaf(w[it].w, hv.w, a3);
    }
    a3 = wave_reduce(a3);
    if (lane == 0) {
        out[row]     = a3 + bout[row];
        out[H + row] = sh[row];
        if (row == 0) out[2 * H] = (float)N;
    }
}

extern "C" void kernel_launch(void* const* d_in, const int* in_sizes, int n_in,
                              void* d_out, int out_size, void* d_ws, size_t ws_size,
                              hipStream_t stream) {
    const float* x     = (const float*)d_in[0];
    const float* s     = (const float*)d_in[1];
    const float* Wih   = (const float*)d_in[2];
    const float* bih   = (const float*)d_in[3];
    const float* Whh   = (const float*)d_in[4];
    const float* bhh   = (const float*)d_in[5];
    const float* whalt = (const float*)d_in[6];
    const float* bhalt = (const float*)d_in[7];
    const float* Wout  = (const float*)d_in[8];
    const float* bout  = (const float*)d_in[9];
    float* out = (float*)d_out;
    float* ws  = (float*)d_ws;

    k_init0<<<NB, TPB, 0, stream>>>(x, s, Wih, bih, Whh, bhh, whalt, ws);
    k_step1<<<NB, TPB, 0, stream>>>(Whh, whalt, bhalt, ws);
    k_tail <<<NB_C, TPB_C, 0, stream>>>(Whh, whalt, bhalt, Wout, bout, ws, out);
}